// Round 3
// baseline (4291.831 us; speedup 1.0000x reference)
//
#include <hip/hip_runtime.h>
#include <hip/hip_bf16.h>
#include <cmath>

typedef __hip_bfloat16 bf16;

#define BB 8
#define VV 321
#define SS 24
#define DD 256
#define HH 8
#define GG 10
#define KTOP 33
#define DFFN 1024
#define BV (BB*VV)            // 2568
#define BSEG (BB*SS)          // 192
#define NROWS (BV*SS)         // 61632  (== BSEG*VV)
#define NE ((size_t)NROWS*DD) // 15777792
#define SCALE 0.17677669529663687f  // 1/sqrt(32)

enum { GF_GELU=1, GF_LOGRELU=2, GF_ABF16=4, GF_RBF16=8, GF_CBF16=16 };

__device__ __forceinline__ float bf2f(bf16 x){ return __bfloat162float(x); }

// ---------------------------------------------------------------------------
// Generic GEMM: C[M,N] = act(A[M,K] @ W[K,N] + bias) (+ residual R)
// A: fp32 or bf16 (GF_ABF16); optional log1p(relu()) on A-load.
// W/bias: fp32 (they are model inputs). R: fp32 or bf16 (GF_RBF16).
// C: fp32 or bf16 (GF_CBF16). fp32 accumulate.
// Tile 64x64, BK=16, 256 threads, 4x4 per thread.
// ---------------------------------------------------------------------------
__global__ __launch_bounds__(256) void gemm_k(
    const void* __restrict__ Ap, const float* __restrict__ W,
    const float* __restrict__ bias, const void* __restrict__ Rp,
    void* __restrict__ Cp, int M, int N, int K, int flags)
{
  __shared__ float As[16][68];   // [k][m]
  __shared__ float Ws[16][68];   // [k][n]
  int tid = threadIdx.x;
  int tx = tid & 15, ty = tid >> 4;
  int m0 = blockIdx.y * 64, n0 = blockIdx.x * 64;
  float acc[4][4];
  #pragma unroll
  for (int i=0;i<4;i++)
    #pragma unroll
    for (int j=0;j<4;j++) acc[i][j]=0.f;

  for (int k0 = 0; k0 < K; k0 += 16) {
    #pragma unroll
    for (int i = 0; i < 4; ++i) {
      int idx = tid + i*256;
      int r = idx >> 4, c = idx & 15;
      int gr = m0 + r;
      float v = 0.f;
      if (gr < M) {
        size_t gi = (size_t)gr*K + (size_t)(k0 + c);
        v = (flags & GF_ABF16) ? bf2f(((const bf16*)Ap)[gi]) : ((const float*)Ap)[gi];
        if (flags & GF_LOGRELU) v = log1pf(fmaxf(v, 0.f));
      }
      As[c][r] = v;
    }
    #pragma unroll
    for (int i = 0; i < 4; ++i) {
      int idx = tid + i*256;
      int c = idx >> 6, j = idx & 63;
      Ws[c][j] = W[(size_t)(k0+c)*N + (size_t)(n0 + j)];
    }
    __syncthreads();
    #pragma unroll
    for (int k = 0; k < 16; ++k) {
      float a[4], b[4];
      #pragma unroll
      for (int i=0;i<4;i++) a[i] = As[k][ty*4+i];
      #pragma unroll
      for (int j=0;j<4;j++) b[j] = Ws[k][tx*4+j];
      #pragma unroll
      for (int i=0;i<4;i++)
        #pragma unroll
        for (int j=0;j<4;j++) acc[i][j] = fmaf(a[i], b[j], acc[i][j]);
    }
    __syncthreads();
  }
  #pragma unroll
  for (int i=0;i<4;i++) {
    int row = m0 + ty*4 + i;
    if (row >= M) continue;
    #pragma unroll
    for (int j=0;j<4;j++) {
      int col = n0 + tx*4 + j;
      float v = acc[i][j] + bias[col];
      if (flags & GF_GELU) v = 0.5f*v*(1.f + erff(v*0.70710678118654752f));
      if (Rp) {
        size_t ri = (size_t)row*N + col;
        v += (flags & GF_RBF16) ? bf2f(((const bf16*)Rp)[ri]) : ((const float*)Rp)[ri];
      }
      size_t ci = (size_t)row*N + col;
      if (flags & GF_CBF16) ((bf16*)Cp)[ci] = __float2bfloat16(v);
      else                  ((float*)Cp)[ci] = v;
    }
  }
}

// ---------------------------------------------------------------------------
// Temporal attention (route 1): per-bv block, S=24, H=8, DH=32.
// Q,K,V bf16 (row = bv*24+s, col = h*32+d); fp32 inside. O overwrites Q.
// ---------------------------------------------------------------------------
__global__ __launch_bounds__(128) void attn1_k(bf16* __restrict__ Q,
                                               const bf16* __restrict__ Kb,
                                               const bf16* __restrict__ Vb)
{
  int bv = blockIdx.x;
  int tid = threadIdx.x;
  __shared__ float qh[24][32], kh[24][32], vh[24][32];
  __shared__ float sc[24][25];
  for (int h = 0; h < HH; ++h) {
    __syncthreads();
    for (int i = tid; i < 24*32; i += 128) {
      int r = i >> 5, c = i & 31;
      size_t base = ((size_t)(bv*24 + r))*DD + h*32 + c;
      qh[r][c] = bf2f(Q[base]);
      kh[r][c] = bf2f(Kb[base]);
      vh[r][c] = bf2f(Vb[base]);
    }
    __syncthreads();
    for (int t = tid; t < 24*24; t += 128) {
      int i = t / 24, j = t % 24;
      float d = 0.f;
      #pragma unroll
      for (int e = 0; e < 32; ++e) d += qh[i][e]*kh[j][e];
      sc[i][j] = d * SCALE;
    }
    __syncthreads();
    if (tid < 24) {
      float mx = -INFINITY;
      for (int j = 0; j < 24; ++j) mx = fmaxf(mx, sc[tid][j]);
      float sm = 0.f;
      for (int j = 0; j < 24; ++j) { float e = expf(sc[tid][j]-mx); sc[tid][j] = e; sm += e; }
      float inv = 1.f/sm;
      for (int j = 0; j < 24; ++j) sc[tid][j] *= inv;
    }
    __syncthreads();
    for (int t = tid; t < 24*32; t += 128) {
      int i = t >> 5, d = t & 31;
      float o = 0.f;
      #pragma unroll
      for (int j = 0; j < 24; ++j) o += sc[i][j]*vh[j][d];
      Q[((size_t)(bv*24 + i))*DD + h*32 + d] = __float2bfloat16(o);
    }
  }
}

// ---------------------------------------------------------------------------
// LayerNorm: bf16 in/out, fp32 g/b, fp32 inside. One wave/row, 4 rows/block.
// ---------------------------------------------------------------------------
__global__ __launch_bounds__(256) void ln_k(const bf16* __restrict__ X, bf16* __restrict__ Y,
                                            const float* __restrict__ g, const float* __restrict__ b,
                                            int nrows)
{
  int row = blockIdx.x*4 + (threadIdx.x >> 6);
  int lane = threadIdx.x & 63;
  if (row >= nrows) return;
  const bf16* xr = X + (size_t)row*DD;
  int c = lane*4;
  float v0 = bf2f(xr[c+0]), v1 = bf2f(xr[c+1]), v2 = bf2f(xr[c+2]), v3 = bf2f(xr[c+3]);
  float s = v0+v1+v2+v3;
  #pragma unroll
  for (int off = 32; off; off >>= 1) s += __shfl_xor(s, off);
  float m = s * (1.f/256.f);
  float d0=v0-m, d1=v1-m, d2=v2-m, d3=v3-m;
  float q = d0*d0+d1*d1+d2*d2+d3*d3;
  #pragma unroll
  for (int off = 32; off; off >>= 1) q += __shfl_xor(q, off);
  float rstd = rsqrtf(q*(1.f/256.f) + 1e-5f);
  bf16* yr = Y + (size_t)row*DD;
  yr[c+0] = __float2bfloat16(d0*rstd*g[c+0] + b[c+0]);
  yr[c+1] = __float2bfloat16(d1*rstd*g[c+1] + b[c+1]);
  yr[c+2] = __float2bfloat16(d2*rstd*g[c+2] + b[c+2]);
  yr[c+3] = __float2bfloat16(d3*rstd*g[c+3] + b[c+3]);
}

// Final LN + permute (B,S,V,D)->(B,V,S,D) + fp32 store
__global__ __launch_bounds__(256) void ln_out_k(const bf16* __restrict__ X, float* __restrict__ out,
                                                const float* __restrict__ g, const float* __restrict__ b)
{
  int row = blockIdx.x*4 + (threadIdx.x >> 6);  // row = bs*321+v, bs=b*24+s
  int lane = threadIdx.x & 63;
  if (row >= NROWS) return;
  const bf16* xr = X + (size_t)row*DD;
  int c = lane*4;
  float v0 = bf2f(xr[c+0]), v1 = bf2f(xr[c+1]), v2 = bf2f(xr[c+2]), v3 = bf2f(xr[c+3]);
  float s = v0+v1+v2+v3;
  #pragma unroll
  for (int off = 32; off; off >>= 1) s += __shfl_xor(s, off);
  float m = s * (1.f/256.f);
  float d0=v0-m, d1=v1-m, d2=v2-m, d3=v3-m;
  float q = d0*d0+d1*d1+d2*d2+d3*d3;
  #pragma unroll
  for (int off = 32; off; off >>= 1) q += __shfl_xor(q, off);
  float rstd = rsqrtf(q*(1.f/256.f) + 1e-5f);
  int bs = row / VV, vv = row % VV;
  int bb = bs / SS, ss = bs % SS;
  float* op = out + (((size_t)bb*VV + vv)*SS + ss)*DD + c;
  op[0] = d0*rstd*g[c+0] + b[c+0];
  op[1] = d1*rstd*g[c+1] + b[c+1];
  op[2] = d2*rstd*g[c+2] + b[c+2];
  op[3] = d3*rstd*g[c+3] + b[c+3];
}

// (B,V,S,D) rows -> (B,S,V,D) rows ; bf16, 8B per thread
__global__ __launch_bounds__(64) void transpose_k(const bf16* __restrict__ X, bf16* __restrict__ Y)
{
  int r2 = blockIdx.x;                 // out row: (b*24+s)*321+v
  int b = r2 / (SS*VV);
  int rem = r2 % (SS*VV);
  int s = rem / VV, v = rem % VV;
  int r1 = (b*VV + v)*SS + s;
  ((uint2*)(Y + (size_t)r2*DD))[threadIdx.x] =
      ((const uint2*)(X + (size_t)r1*DD))[threadIdx.x];
}

// ---------------------------------------------------------------------------
// Scores + top-33 (desc, ties -> lower index, matching jax.lax.top_k).
// One wave per (bs,h,g). qS fp32 row = (s*10+g); kS bf16 row = bs*321+v.
// ---------------------------------------------------------------------------
__global__ __launch_bounds__(64) void topk_k(const float* __restrict__ qS,
                                             const bf16* __restrict__ kS,
                                             int* __restrict__ idxOut)
{
  int bid = blockIdx.x;                // (bs*8+h)*10+g
  int g = bid % GG;
  int h = (bid / GG) % HH;
  int bs = bid / (GG*HH);
  int s = bs % SS;
  int lane = threadIdx.x;
  __shared__ float qv[32];
  if (lane < 32) qv[lane] = qS[((size_t)(s*GG + g))*DD + h*32 + lane];
  __syncthreads();
  float sc[6];
  #pragma unroll
  for (int j = 0; j < 6; ++j) {
    int v = lane + j*64;
    if (v < VV) {
      const bf16* kp = kS + ((size_t)bs*VV + v)*DD + h*32;
      float d = 0.f;
      #pragma unroll
      for (int e = 0; e < 32; ++e) d += qv[e]*bf2f(kp[e]);
      sc[j] = d * SCALE;
    } else sc[j] = -INFINITY;
  }
  for (int it = 0; it < KTOP; ++it) {
    float bv = sc[0]; int bj = 0;
    #pragma unroll
    for (int j = 1; j < 6; ++j) if (sc[j] > bv) { bv = sc[j]; bj = j; }
    int bi = lane + bj*64;
    #pragma unroll
    for (int off = 32; off; off >>= 1) {
      float ov = __shfl_down(bv, off);
      int   oi = __shfl_down(bi, off);
      if (ov > bv || (ov == bv && oi < bi)) { bv = ov; bi = oi; }
    }
    bi = __shfl(bi, 0);
    if (lane == 0) idxOut[(size_t)bid*KTOP + it] = bi;
    if ((bi & 63) == lane) sc[bi >> 6] = -INFINITY;
  }
}

// ---------------------------------------------------------------------------
// Grouped conv over gathered top-k + min/max/exp -> feat (bs,G,256) fp32
// Block = (bs,g), thread = h*32+d. vS bf16, cw/cb fp32.
// ---------------------------------------------------------------------------
__global__ __launch_bounds__(256) void conv_k(const bf16* __restrict__ vS,
                                              const int* __restrict__ idx,
                                              const float* __restrict__ cw,
                                              const float* __restrict__ cb,
                                              float* __restrict__ feat)
{
  int bid = blockIdx.x;
  int bs = bid / GG, g = bid % GG;
  int tid = threadIdx.x;
  int h = tid >> 5, d = tid & 31;
  __shared__ float cws[KTOP];
  __shared__ int idl[HH][KTOP];
  __shared__ float ms[256];
  if (tid < KTOP) cws[tid] = cw[g*KTOP + tid];
  for (int i = tid; i < HH*KTOP; i += 256) {
    int hh = i / KTOP, k = i % KTOP;
    int ix = idx[(((size_t)bs*HH + hh)*GG + g)*KTOP + k];
    idl[hh][k] = (ix < 0) ? 0 : (ix >= VV ? VV-1 : ix);   // defensive clamp
  }
  __syncthreads();
  float acc = 0.f;
  #pragma unroll
  for (int k = 0; k < KTOP; ++k)
    acc += bf2f(vS[((size_t)bs*VV + idl[h][k])*DD + h*32 + d]) * cws[k];
  acc += cb[g];
  ms[tid] = acc;
  __syncthreads();
  float mn = acc, mx = acc;
  #pragma unroll
  for (int j = 0; j < 32; ++j) {
    float t = ms[h*32 + j];
    mn = fminf(mn, t); mx = fmaxf(mx, t);
  }
  float xn = expf((acc - mn) / fmaxf(mx - mn, 1e-6f));
  feat[((size_t)bs*GG + g)*DD + h*32 + d] = xn;
}

// ---------------------------------------------------------------------------
// Cross attention (route 2): 321 bf16 queries vs 10 fp32 keys per bs.
// O overwrites Q (bf16).
// ---------------------------------------------------------------------------
__global__ __launch_bounds__(256) void attn2_k(bf16* __restrict__ Q,
                                               const float* __restrict__ KR,
                                               const float* __restrict__ VR)
{
  int bs = blockIdx.x;
  int tid = threadIdx.x;
  __shared__ float kr[GG][DD], vr[GG][DD];
  for (int i = tid; i < GG*DD; i += 256) {
    int r = i >> 8, c = i & 255;
    kr[r][c] = KR[((size_t)bs*GG + r)*DD + c];
    vr[r][c] = VR[((size_t)bs*GG + r)*DD + c];
  }
  __syncthreads();
  for (int task = tid; task < VV*HH; task += 256) {
    int v = task >> 3, h = task & 7;
    bf16* qp = Q + ((size_t)bs*VV + v)*DD + h*32;
    float qr[32];
    #pragma unroll
    for (int d = 0; d < 32; ++d) qr[d] = bf2f(qp[d]);
    float sv[GG];
    float mx = -INFINITY;
    #pragma unroll
    for (int gi = 0; gi < GG; ++gi) {
      float dsum = 0.f;
      #pragma unroll
      for (int d = 0; d < 32; ++d) dsum += qr[d]*kr[gi][h*32+d];
      sv[gi] = dsum * SCALE;
      mx = fmaxf(mx, sv[gi]);
    }
    float ssum = 0.f;
    #pragma unroll
    for (int gi = 0; gi < GG; ++gi) { sv[gi] = expf(sv[gi]-mx); ssum += sv[gi]; }
    float inv = 1.f/ssum;
    float o[32];
    #pragma unroll
    for (int d = 0; d < 32; ++d) o[d] = 0.f;
    #pragma unroll
    for (int gi = 0; gi < GG; ++gi) {
      float p = sv[gi]*inv;
      #pragma unroll
      for (int d = 0; d < 32; ++d) o[d] += p*vr[gi][h*32+d];
    }
    #pragma unroll
    for (int d = 0; d < 32; ++d) qp[d] = __float2bfloat16(o[d]);
  }
}

// ---------------------------------------------------------------------------
extern "C" void kernel_launch(void* const* d_in, const int* in_sizes, int n_in,
                              void* d_out, int out_size, void* d_ws, size_t ws_size,
                              hipStream_t stream)
{
  const float* queries=(const float*)d_in[0];
  const float* t_wq=(const float*)d_in[1];  const float* t_bq=(const float*)d_in[2];
  const float* t_wk=(const float*)d_in[3];  const float* t_bk=(const float*)d_in[4];
  const float* t_wv=(const float*)d_in[5];  const float* t_bv=(const float*)d_in[6];
  const float* t_wo=(const float*)d_in[7];  const float* t_bo=(const float*)d_in[8];
  const float* s_wq=(const float*)d_in[9];  const float* s_bq=(const float*)d_in[10];
  const float* s_wk=(const float*)d_in[11]; const float* s_bk=(const float*)d_in[12];
  const float* s_wv=(const float*)d_in[13]; const float* s_bv=(const float*)d_in[14];
  const float* s_wo=(const float*)d_in[15]; const float* s_bo=(const float*)d_in[16];
  const float* cluster=(const float*)d_in[17];
  const float* conv_w=(const float*)d_in[18]; const float* conv_b=(const float*)d_in[19];
  const float* r_wq=(const float*)d_in[20]; const float* r_bq=(const float*)d_in[21];
  const float* r_wk=(const float*)d_in[22]; const float* r_bk=(const float*)d_in[23];
  const float* r_wv=(const float*)d_in[24]; const float* r_bv=(const float*)d_in[25];
  const float* r_wo=(const float*)d_in[26]; const float* r_bo=(const float*)d_in[27];
  const float* ln_t1_g=(const float*)d_in[28]; const float* ln_t1_b=(const float*)d_in[29];
  const float* ln_t2_g=(const float*)d_in[30]; const float* ln_t2_b=(const float*)d_in[31];
  const float* ln_d1_g=(const float*)d_in[32]; const float* ln_d1_b=(const float*)d_in[33];
  const float* ln_d2_g=(const float*)d_in[34]; const float* ln_d2_b=(const float*)d_in[35];
  const float* ft_w1=(const float*)d_in[36]; const float* ft_b1=(const float*)d_in[37];
  const float* ft_w2=(const float*)d_in[38]; const float* ft_b2=(const float*)d_in[39];
  const float* fd_w1=(const float*)d_in[40]; const float* fd_b1=(const float*)d_in[41];
  const float* fd_w2=(const float*)d_in[42]; const float* fd_b2=(const float*)d_in[43];

  // Workspace: 3 big bf16 buffers (94.7 MB) + fp32 smalls (~10 MB) = ~105 MB
  bf16* Ab = (bf16*)d_ws;
  bf16* Bb = Ab + NE;
  bf16* Cb = Bb + NE;
  float* QSf   = (float*)(Cb + NE);        // 240*256
  float* FEATf = QSf + 240*256;            // 1920*256
  float* ROUTEf= FEATf + 1920*256;         // 1920*256
  float* KRf   = ROUTEf + 1920*256;        // 1920*256
  float* VRf   = KRf + 1920*256;           // 1920*256
  int*   IDXb  = (int*)(VRf + 1920*256);   // 15360*33 ints

  dim3 blk(256);
  dim3 gN256(4, (NROWS+63)/64);           // (4, 963)
  dim3 gSmall(4, 30);                     // M=1920
  dim3 gQ(4, 4);                          // M=240
  const int STRIPE = NROWS/4;             // 15408
  dim3 gF1(16, (STRIPE+63)/64);           // N=1024
  dim3 gF2(4,  (STRIPE+63)/64);           // N=256

  const int AB = GF_ABF16, CB16 = GF_CBF16, RB = GF_RBF16;

  // ---- Route 1: temporal ----
  gemm_k<<<gN256, blk, 0, stream>>>(queries, t_wq, t_bq, nullptr, Ab, NROWS, 256, 256, CB16);
  gemm_k<<<gN256, blk, 0, stream>>>(queries, t_wk, t_bk, nullptr, Bb, NROWS, 256, 256, CB16);
  gemm_k<<<gN256, blk, 0, stream>>>(queries, t_wv, t_bv, nullptr, Cb, NROWS, 256, 256, CB16);
  attn1_k<<<BV, 128, 0, stream>>>(Ab, Bb, Cb);                        // O -> Ab
  gemm_k<<<gN256, blk, 0, stream>>>(Ab, t_wo, t_bo, queries, Bb, NROWS, 256, 256, AB|CB16); // + fp32 residual
  ln_k<<<NROWS/4, blk, 0, stream>>>(Bb, Ab, ln_t1_g, ln_t1_b, NROWS); // x1 -> Ab
  for (int st = 0; st < 4; ++st) {
    size_t ro = (size_t)st * STRIPE * DD;
    gemm_k<<<gF1, blk, 0, stream>>>(Ab + ro, ft_w1, ft_b1, nullptr, Cb, STRIPE, 1024, 256, AB|GF_GELU|CB16);
    gemm_k<<<gF2, blk, 0, stream>>>(Cb, ft_w2, ft_b2, Ab + ro, Bb + ro, STRIPE, 256, 1024, AB|RB|CB16);
  }
  ln_k<<<NROWS/4, blk, 0, stream>>>(Bb, Ab, ln_t2_g, ln_t2_b, NROWS); // x -> Ab

  // ---- Route 2: dimensional ----
  transpose_k<<<NROWS, 64, 0, stream>>>(Ab, Bb);                      // xd -> Bb
  gemm_k<<<gN256, blk, 0, stream>>>(Bb, s_wk, s_bk, nullptr, Ab, NROWS, 256, 256, AB|GF_LOGRELU|CB16); // kS
  gemm_k<<<gN256, blk, 0, stream>>>(Bb, s_wv, s_bv, nullptr, Cb, NROWS, 256, 256, AB|GF_LOGRELU|CB16); // vS
  gemm_k<<<gQ, blk, 0, stream>>>(cluster, s_wq, s_bq, nullptr, QSf, 240, 256, 256, 0);
  topk_k<<<BSEG*HH*GG, 64, 0, stream>>>(QSf, Ab, IDXb);
  conv_k<<<BSEG*GG, blk, 0, stream>>>(Cb, IDXb, conv_w, conv_b, FEATf);
  gemm_k<<<gSmall, blk, 0, stream>>>(FEATf, s_wo, s_bo, nullptr, ROUTEf, 1920, 256, 256, 0);
  gemm_k<<<gN256, blk, 0, stream>>>(Bb, r_wq, r_bq, nullptr, Ab, NROWS, 256, 256, AB|CB16); // qD -> Ab
  gemm_k<<<gSmall, blk, 0, stream>>>(ROUTEf, r_wk, r_bk, nullptr, KRf, 1920, 256, 256, 0);
  gemm_k<<<gSmall, blk, 0, stream>>>(ROUTEf, r_wv, r_bv, nullptr, VRf, 1920, 256, 256, 0);
  attn2_k<<<BSEG, blk, 0, stream>>>(Ab, KRf, VRf);                    // O -> Ab
  gemm_k<<<gN256, blk, 0, stream>>>(Ab, r_wo, r_bo, Bb, Cb, NROWS, 256, 256, AB|RB|CB16);  // preLN -> Cb
  ln_k<<<NROWS/4, blk, 0, stream>>>(Cb, Ab, ln_d1_g, ln_d1_b, NROWS); // x1d -> Ab
  for (int st = 0; st < 4; ++st) {
    size_t ro = (size_t)st * STRIPE * DD;
    gemm_k<<<gF1, blk, 0, stream>>>(Ab + ro, fd_w1, fd_b1, nullptr, Bb, STRIPE, 1024, 256, AB|GF_GELU|CB16);
    gemm_k<<<gF2, blk, 0, stream>>>(Bb, fd_w2, fd_b2, Ab + ro, Cb + ro, STRIPE, 256, 1024, AB|RB|CB16);
  }
  ln_out_k<<<NROWS/4, blk, 0, stream>>>(Cb, (float*)d_out, ln_d2_g, ln_d2_b);
}

// Round 4
// 2102.514 us; speedup vs baseline: 2.0413x; 2.0413x over previous
//
#include <hip/hip_runtime.h>
#include <hip/hip_bf16.h>
#include <cmath>

typedef __hip_bfloat16 bf16;
typedef __attribute__((ext_vector_type(8))) short short8;
typedef __attribute__((ext_vector_type(4))) float f32x4;

#define BB 8
#define VV 321
#define SS 24
#define DD 256
#define HH 8
#define GG 10
#define KTOP 33
#define DFFN 1024
#define BV (BB*VV)            // 2568
#define BSEG (BB*SS)          // 192
#define NROWS (BV*SS)         // 61632  (== BSEG*VV)
#define NE ((size_t)NROWS*DD) // 15777792
#define SCALE 0.17677669529663687f  // 1/sqrt(32)
#define LSTR 56               // LDS row stride (bf16 elems): 112B rows, 16B-aligned, 2-way max bank alias

enum { GF_GELU=1, GF_LOGRELU=2, GF_ABF16=4, GF_RBF16=8, GF_CBF16=16 };
enum { MF_GELU=1, MF_LOGRELU=2, MF_AF32=4, MF_RF32=8, MF_CF32=16 };

__device__ __forceinline__ float bf2f(bf16 x){ return __bfloat162float(x); }
__device__ __forceinline__ unsigned short f2bfbits(float f){
  bf16 h = __float2bfloat16(f);
  return *(unsigned short*)&h;
}
__device__ __forceinline__ float bfbits2f(unsigned short u){
  bf16 h; *(unsigned short*)&h = u; return __bfloat162float(h);
}

// ---------------------------------------------------------------------------
// Weight prep: fp32 W[K][N] -> bf16 W^T[N][K] into pool. 32x32 tiles via LDS.
// ---------------------------------------------------------------------------
struct WPrep {
  const float* src[12];
  int K[12], N[12], dstoff[12], tileoff[13];
};

__global__ __launch_bounds__(256) void prep_w_k(WPrep p, bf16* __restrict__ pool)
{
  __shared__ float t[32][33];
  int b = blockIdx.x;
  int m = 0;
  while (b >= p.tileoff[m+1]) ++m;
  int tt = b - p.tileoff[m];
  int K = p.K[m], N = p.N[m];
  int nc = N >> 5;
  int tr = tt / nc, tc = tt % nc;      // k-tile, n-tile
  const float* src = p.src[m];
  int tid = threadIdx.x;
  int r = tid >> 3, c = (tid & 7) * 4;
  float4 v = *(const float4*)&src[(size_t)(tr*32 + r)*N + tc*32 + c];
  t[r][c+0]=v.x; t[r][c+1]=v.y; t[r][c+2]=v.z; t[r][c+3]=v.w;
  __syncthreads();
  bf16* dst = pool + p.dstoff[m];
  size_t base = (size_t)(tc*32 + r)*K + tr*32 + c;
  #pragma unroll
  for (int i=0;i<4;++i) dst[base+i] = __float2bfloat16(t[c+i][r]);
}

// ---------------------------------------------------------------------------
// MFMA GEMM: C[M,N] = act(A[M,K] @ W[K,N] + bias) (+ residual)
// A: bf16 (or fp32 w/ MF_AF32), optional log1p(relu) on load.
// Wt: bf16 [N][K] (pre-transposed). bias fp32. C bf16 (or fp32 w/ MF_CF32).
// 128x128 tile, BK=32, 256 threads (4 waves), wave = 64x64, 4x4 16x16 MFMAs.
// N must be a multiple of 128; K a multiple of 32; M fringe guarded.
// ---------------------------------------------------------------------------
__global__ __launch_bounds__(256) void mgemm_k(
    const void* __restrict__ Ap, const bf16* __restrict__ Wt,
    const float* __restrict__ bias, const void* __restrict__ Rp,
    void* __restrict__ Cp, int M, int N, int K, int flags)
{
  __shared__ __align__(16) unsigned short As[128*LSTR];
  __shared__ __align__(16) unsigned short Bs[128*LSTR];
  int tid = threadIdx.x;
  int wave = tid >> 6, lane = tid & 63;
  int quad = lane >> 4, l16 = lane & 15;
  int wr = wave >> 1, wc = wave & 1;
  int m0 = blockIdx.y * 128, n0 = blockIdx.x * 128;

  f32x4 acc[4][4];
  #pragma unroll
  for (int i=0;i<4;++i)
    #pragma unroll
    for (int j=0;j<4;++j) acc[i][j] = (f32x4){0.f,0.f,0.f,0.f};

  int r_ = tid >> 2;          // 0..63
  int cg = (tid & 3) * 8;     // elem offset 0,8,16,24

  for (int k0 = 0; k0 < K; k0 += 32) {
    // ---- stage A tile (128 x 32) ----
    #pragma unroll
    for (int it = 0; it < 2; ++it) {
      int row = r_ + it*64;
      int gm = m0 + row;
      unsigned short v[8];
      if (gm < M) {
        if (flags & MF_AF32) {
          const float* ap = (const float*)Ap + (size_t)gm*K + k0 + cg;
          float4 f0 = *(const float4*)ap;
          float4 f1 = *(const float4*)(ap+4);
          float fv[8] = {f0.x,f0.y,f0.z,f0.w,f1.x,f1.y,f1.z,f1.w};
          #pragma unroll
          for (int j=0;j<8;++j) {
            float f = fv[j];
            if (flags & MF_LOGRELU) f = log1pf(fmaxf(f,0.f));
            v[j] = f2bfbits(f);
          }
        } else {
          const unsigned short* ap = (const unsigned short*)Ap + (size_t)gm*K + k0 + cg;
          uint4 u = *(const uint4*)ap;
          *(uint4*)v = u;
          if (flags & MF_LOGRELU) {
            #pragma unroll
            for (int j=0;j<8;++j) v[j] = f2bfbits(log1pf(fmaxf(bfbits2f(v[j]),0.f)));
          }
        }
      } else {
        #pragma unroll
        for (int j=0;j<8;++j) v[j] = 0;
      }
      *(uint4*)&As[row*LSTR + cg] = *(uint4*)v;
    }
    // ---- stage Wt tile (128 x 32), N multiple of 128 -> no guard ----
    #pragma unroll
    for (int it = 0; it < 2; ++it) {
      int row = r_ + it*64;
      const unsigned short* wp = (const unsigned short*)Wt + (size_t)(n0+row)*K + k0 + cg;
      *(uint4*)&Bs[row*LSTR + cg] = *(const uint4*)wp;
    }
    __syncthreads();
    short8 a[4], b[4];
    #pragma unroll
    for (int i=0;i<4;++i)
      a[i] = *(const short8*)&As[(wr*64 + i*16 + l16)*LSTR + quad*8];
    #pragma unroll
    for (int j=0;j<4;++j)
      b[j] = *(const short8*)&Bs[(wc*64 + j*16 + l16)*LSTR + quad*8];
    #pragma unroll
    for (int i=0;i<4;++i)
      #pragma unroll
      for (int j=0;j<4;++j)
        acc[i][j] = __builtin_amdgcn_mfma_f32_16x16x32_bf16(a[i], b[j], acc[i][j], 0, 0, 0);
    __syncthreads();
  }

  // ---- epilogue: D[row=quad*4+r][col=l16] per 16x16 tile ----
  #pragma unroll
  for (int i=0;i<4;++i) {
    int mbase = m0 + wr*64 + i*16 + quad*4;
    #pragma unroll
    for (int j=0;j<4;++j) {
      int n = n0 + wc*64 + j*16 + l16;
      float bv = bias[n];
      #pragma unroll
      for (int r=0;r<4;++r) {
        int mm = mbase + r;
        if (mm >= M) continue;
        float v = acc[i][j][r] + bv;
        if (flags & MF_GELU) v = 0.5f*v*(1.f + erff(v*0.70710678118654752f));
        if (Rp) {
          size_t ri = (size_t)mm*N + n;
          v += (flags & MF_RF32) ? ((const float*)Rp)[ri] : bf2f(((const bf16*)Rp)[ri]);
        }
        size_t ci = (size_t)mm*N + n;
        if (flags & MF_CF32) ((float*)Cp)[ci] = v;
        else                 ((bf16*)Cp)[ci] = __float2bfloat16(v);
      }
    }
  }
}

// ---------------------------------------------------------------------------
// Old fp32 VALU GEMM — kept for the tiny route GEMMs (M<=1920), fp32 in/out.
// ---------------------------------------------------------------------------
__global__ __launch_bounds__(256) void gemm_k(
    const void* __restrict__ Ap, const float* __restrict__ W,
    const float* __restrict__ bias, const void* __restrict__ Rp,
    void* __restrict__ Cp, int M, int N, int K, int flags)
{
  __shared__ float As[16][68];
  __shared__ float Ws[16][68];
  int tid = threadIdx.x;
  int tx = tid & 15, ty = tid >> 4;
  int m0 = blockIdx.y * 64, n0 = blockIdx.x * 64;
  float acc[4][4];
  #pragma unroll
  for (int i=0;i<4;i++)
    #pragma unroll
    for (int j=0;j<4;j++) acc[i][j]=0.f;

  for (int k0 = 0; k0 < K; k0 += 16) {
    #pragma unroll
    for (int i = 0; i < 4; ++i) {
      int idx = tid + i*256;
      int r = idx >> 4, c = idx & 15;
      int gr = m0 + r;
      float v = 0.f;
      if (gr < M) {
        size_t gi = (size_t)gr*K + (size_t)(k0 + c);
        v = (flags & GF_ABF16) ? bf2f(((const bf16*)Ap)[gi]) : ((const float*)Ap)[gi];
        if (flags & GF_LOGRELU) v = log1pf(fmaxf(v, 0.f));
      }
      As[c][r] = v;
    }
    #pragma unroll
    for (int i = 0; i < 4; ++i) {
      int idx = tid + i*256;
      int c = idx >> 6, j = idx & 63;
      Ws[c][j] = W[(size_t)(k0+c)*N + (size_t)(n0 + j)];
    }
    __syncthreads();
    #pragma unroll
    for (int k = 0; k < 16; ++k) {
      float a[4], b[4];
      #pragma unroll
      for (int i=0;i<4;i++) a[i] = As[k][ty*4+i];
      #pragma unroll
      for (int j=0;j<4;j++) b[j] = Ws[k][tx*4+j];
      #pragma unroll
      for (int i=0;i<4;i++)
        #pragma unroll
        for (int j=0;j<4;j++) acc[i][j] = fmaf(a[i], b[j], acc[i][j]);
    }
    __syncthreads();
  }
  #pragma unroll
  for (int i=0;i<4;i++) {
    int row = m0 + ty*4 + i;
    if (row >= M) continue;
    #pragma unroll
    for (int j=0;j<4;j++) {
      int col = n0 + tx*4 + j;
      float v = acc[i][j] + bias[col];
      if (flags & GF_GELU) v = 0.5f*v*(1.f + erff(v*0.70710678118654752f));
      if (Rp) {
        size_t ri = (size_t)row*N + col;
        v += (flags & GF_RBF16) ? bf2f(((const bf16*)Rp)[ri]) : ((const float*)Rp)[ri];
      }
      size_t ci = (size_t)row*N + col;
      if (flags & GF_CBF16) ((bf16*)Cp)[ci] = __float2bfloat16(v);
      else                  ((float*)Cp)[ci] = v;
    }
  }
}

// ---------------------------------------------------------------------------
// Temporal attention (route 1): per-bv block, S=24, H=8, DH=32. bf16 I/O.
// ---------------------------------------------------------------------------
__global__ __launch_bounds__(128) void attn1_k(bf16* __restrict__ Q,
                                               const bf16* __restrict__ Kb,
                                               const bf16* __restrict__ Vb)
{
  int bv = blockIdx.x;
  int tid = threadIdx.x;
  __shared__ float qh[24][32], kh[24][32], vh[24][32];
  __shared__ float sc[24][25];
  for (int h = 0; h < HH; ++h) {
    __syncthreads();
    for (int i = tid; i < 24*32; i += 128) {
      int r = i >> 5, c = i & 31;
      size_t base = ((size_t)(bv*24 + r))*DD + h*32 + c;
      qh[r][c] = bf2f(Q[base]);
      kh[r][c] = bf2f(Kb[base]);
      vh[r][c] = bf2f(Vb[base]);
    }
    __syncthreads();
    for (int t = tid; t < 24*24; t += 128) {
      int i = t / 24, j = t % 24;
      float d = 0.f;
      #pragma unroll
      for (int e = 0; e < 32; ++e) d += qh[i][e]*kh[j][e];
      sc[i][j] = d * SCALE;
    }
    __syncthreads();
    if (tid < 24) {
      float mx = -INFINITY;
      for (int j = 0; j < 24; ++j) mx = fmaxf(mx, sc[tid][j]);
      float sm = 0.f;
      for (int j = 0; j < 24; ++j) { float e = expf(sc[tid][j]-mx); sc[tid][j] = e; sm += e; }
      float inv = 1.f/sm;
      for (int j = 0; j < 24; ++j) sc[tid][j] *= inv;
    }
    __syncthreads();
    for (int t = tid; t < 24*32; t += 128) {
      int i = t >> 5, d = t & 31;
      float o = 0.f;
      #pragma unroll
      for (int j = 0; j < 24; ++j) o += sc[i][j]*vh[j][d];
      Q[((size_t)(bv*24 + i))*DD + h*32 + d] = __float2bfloat16(o);
    }
  }
}

// ---------------------------------------------------------------------------
// LayerNorm: bf16 in/out, fp32 g/b + math. One wave/row, 4 rows/block.
// ---------------------------------------------------------------------------
__global__ __launch_bounds__(256) void ln_k(const bf16* __restrict__ X, bf16* __restrict__ Y,
                                            const float* __restrict__ g, const float* __restrict__ b,
                                            int nrows)
{
  int row = blockIdx.x*4 + (threadIdx.x >> 6);
  int lane = threadIdx.x & 63;
  if (row >= nrows) return;
  const bf16* xr = X + (size_t)row*DD;
  int c = lane*4;
  float v0 = bf2f(xr[c+0]), v1 = bf2f(xr[c+1]), v2 = bf2f(xr[c+2]), v3 = bf2f(xr[c+3]);
  float s = v0+v1+v2+v3;
  #pragma unroll
  for (int off = 32; off; off >>= 1) s += __shfl_xor(s, off);
  float m = s * (1.f/256.f);
  float d0=v0-m, d1=v1-m, d2=v2-m, d3=v3-m;
  float q = d0*d0+d1*d1+d2*d2+d3*d3;
  #pragma unroll
  for (int off = 32; off; off >>= 1) q += __shfl_xor(q, off);
  float rstd = rsqrtf(q*(1.f/256.f) + 1e-5f);
  bf16* yr = Y + (size_t)row*DD;
  yr[c+0] = __float2bfloat16(d0*rstd*g[c+0] + b[c+0]);
  yr[c+1] = __float2bfloat16(d1*rstd*g[c+1] + b[c+1]);
  yr[c+2] = __float2bfloat16(d2*rstd*g[c+2] + b[c+2]);
  yr[c+3] = __float2bfloat16(d3*rstd*g[c+3] + b[c+3]);
}

// Final LN + permute (B,S,V,D)->(B,V,S,D) + fp32 store
__global__ __launch_bounds__(256) void ln_out_k(const bf16* __restrict__ X, float* __restrict__ out,
                                                const float* __restrict__ g, const float* __restrict__ b)
{
  int row = blockIdx.x*4 + (threadIdx.x >> 6);  // row = bs*321+v, bs=b*24+s
  int lane = threadIdx.x & 63;
  if (row >= NROWS) return;
  const bf16* xr = X + (size_t)row*DD;
  int c = lane*4;
  float v0 = bf2f(xr[c+0]), v1 = bf2f(xr[c+1]), v2 = bf2f(xr[c+2]), v3 = bf2f(xr[c+3]);
  float s = v0+v1+v2+v3;
  #pragma unroll
  for (int off = 32; off; off >>= 1) s += __shfl_xor(s, off);
  float m = s * (1.f/256.f);
  float d0=v0-m, d1=v1-m, d2=v2-m, d3=v3-m;
  float q = d0*d0+d1*d1+d2*d2+d3*d3;
  #pragma unroll
  for (int off = 32; off; off >>= 1) q += __shfl_xor(q, off);
  float rstd = rsqrtf(q*(1.f/256.f) + 1e-5f);
  int bs = row / VV, vv = row % VV;
  int bb = bs / SS, ss = bs % SS;
  float* op = out + (((size_t)bb*VV + vv)*SS + ss)*DD + c;
  op[0] = d0*rstd*g[c+0] + b[c+0];
  op[1] = d1*rstd*g[c+1] + b[c+1];
  op[2] = d2*rstd*g[c+2] + b[c+2];
  op[3] = d3*rstd*g[c+3] + b[c+3];
}

// (B,V,S,D) rows -> (B,S,V,D) rows ; bf16, 8B per thread
__global__ __launch_bounds__(64) void transpose_k(const bf16* __restrict__ X, bf16* __restrict__ Y)
{
  int r2 = blockIdx.x;
  int b = r2 / (SS*VV);
  int rem = r2 % (SS*VV);
  int s = rem / VV, v = rem % VV;
  int r1 = (b*VV + v)*SS + s;
  ((uint2*)(Y + (size_t)r2*DD))[threadIdx.x] =
      ((const uint2*)(X + (size_t)r1*DD))[threadIdx.x];
}

// ---------------------------------------------------------------------------
// Scores + top-33 (desc, ties -> lower index). One wave per (bs,h,g).
// ---------------------------------------------------------------------------
__global__ __launch_bounds__(64) void topk_k(const float* __restrict__ qS,
                                             const bf16* __restrict__ kS,
                                             int* __restrict__ idxOut)
{
  int bid = blockIdx.x;                // (bs*8+h)*10+g
  int g = bid % GG;
  int h = (bid / GG) % HH;
  int bs = bid / (GG*HH);
  int s = bs % SS;
  int lane = threadIdx.x;
  __shared__ float qv[32];
  if (lane < 32) qv[lane] = qS[((size_t)(s*GG + g))*DD + h*32 + lane];
  __syncthreads();
  float sc[6];
  #pragma unroll
  for (int j = 0; j < 6; ++j) {
    int v = lane + j*64;
    if (v < VV) {
      const bf16* kp = kS + ((size_t)bs*VV + v)*DD + h*32;
      float d = 0.f;
      #pragma unroll
      for (int e = 0; e < 32; ++e) d += qv[e]*bf2f(kp[e]);
      sc[j] = d * SCALE;
    } else sc[j] = -INFINITY;
  }
  for (int it = 0; it < KTOP; ++it) {
    float bv = sc[0]; int bj = 0;
    #pragma unroll
    for (int j = 1; j < 6; ++j) if (sc[j] > bv) { bv = sc[j]; bj = j; }
    int bi = lane + bj*64;
    #pragma unroll
    for (int off = 32; off; off >>= 1) {
      float ov = __shfl_down(bv, off);
      int   oi = __shfl_down(bi, off);
      if (ov > bv || (ov == bv && oi < bi)) { bv = ov; bi = oi; }
    }
    bi = __shfl(bi, 0);
    if (lane == 0) idxOut[(size_t)bid*KTOP + it] = bi;
    if ((bi & 63) == lane) sc[bi >> 6] = -INFINITY;
  }
}

// ---------------------------------------------------------------------------
// Grouped conv + min/max/exp -> feat (bs,G,256) fp32
// ---------------------------------------------------------------------------
__global__ __launch_bounds__(256) void conv_k(const bf16* __restrict__ vS,
                                              const int* __restrict__ idx,
                                              const float* __restrict__ cw,
                                              const float* __restrict__ cb,
                                              float* __restrict__ feat)
{
  int bid = blockIdx.x;
  int bs = bid / GG, g = bid % GG;
  int tid = threadIdx.x;
  int h = tid >> 5, d = tid & 31;
  __shared__ float cws[KTOP];
  __shared__ int idl[HH][KTOP];
  __shared__ float ms[256];
  if (tid < KTOP) cws[tid] = cw[g*KTOP + tid];
  for (int i = tid; i < HH*KTOP; i += 256) {
    int hh = i / KTOP, k = i % KTOP;
    int ix = idx[(((size_t)bs*HH + hh)*GG + g)*KTOP + k];
    idl[hh][k] = (ix < 0) ? 0 : (ix >= VV ? VV-1 : ix);
  }
  __syncthreads();
  float acc = 0.f;
  #pragma unroll
  for (int k = 0; k < KTOP; ++k)
    acc += bf2f(vS[((size_t)bs*VV + idl[h][k])*DD + h*32 + d]) * cws[k];
  acc += cb[g];
  ms[tid] = acc;
  __syncthreads();
  float mn = acc, mx = acc;
  #pragma unroll
  for (int j = 0; j < 32; ++j) {
    float t = ms[h*32 + j];
    mn = fminf(mn, t); mx = fmaxf(mx, t);
  }
  float xn = expf((acc - mn) / fmaxf(mx - mn, 1e-6f));
  feat[((size_t)bs*GG + g)*DD + h*32 + d] = xn;
}

// ---------------------------------------------------------------------------
// Cross attention (route 2): 321 bf16 queries vs 10 fp32 keys per bs.
// ---------------------------------------------------------------------------
__global__ __launch_bounds__(256) void attn2_k(bf16* __restrict__ Q,
                                               const float* __restrict__ KR,
                                               const float* __restrict__ VR)
{
  int bs = blockIdx.x;
  int tid = threadIdx.x;
  __shared__ float kr[GG][DD], vr[GG][DD];
  for (int i = tid; i < GG*DD; i += 256) {
    int r = i >> 8, c = i & 255;
    kr[r][c] = KR[((size_t)bs*GG + r)*DD + c];
    vr[r][c] = VR[((size_t)bs*GG + r)*DD + c];
  }
  __syncthreads();
  for (int task = tid; task < VV*HH; task += 256) {
    int v = task >> 3, h = task & 7;
    bf16* qp = Q + ((size_t)bs*VV + v)*DD + h*32;
    float qr[32];
    #pragma unroll
    for (int d = 0; d < 32; ++d) qr[d] = bf2f(qp[d]);
    float sv[GG];
    float mx = -INFINITY;
    #pragma unroll
    for (int gi = 0; gi < GG; ++gi) {
      float dsum = 0.f;
      #pragma unroll
      for (int d = 0; d < 32; ++d) dsum += qr[d]*kr[gi][h*32+d];
      sv[gi] = dsum * SCALE;
      mx = fmaxf(mx, sv[gi]);
    }
    float ssum = 0.f;
    #pragma unroll
    for (int gi = 0; gi < GG; ++gi) { sv[gi] = expf(sv[gi]-mx); ssum += sv[gi]; }
    float inv = 1.f/ssum;
    float o[32];
    #pragma unroll
    for (int d = 0; d < 32; ++d) o[d] = 0.f;
    #pragma unroll
    for (int gi = 0; gi < GG; ++gi) {
      float p = sv[gi]*inv;
      #pragma unroll
      for (int d = 0; d < 32; ++d) o[d] += p*vr[gi][h*32+d];
    }
    #pragma unroll
    for (int d = 0; d < 32; ++d) qp[d] = __float2bfloat16(o[d]);
  }
}

// ---------------------------------------------------------------------------
extern "C" void kernel_launch(void* const* d_in, const int* in_sizes, int n_in,
                              void* d_out, int out_size, void* d_ws, size_t ws_size,
                              hipStream_t stream)
{
  const float* queries=(const float*)d_in[0];
  const float* t_wq=(const float*)d_in[1];  const float* t_bq=(const float*)d_in[2];
  const float* t_wk=(const float*)d_in[3];  const float* t_bk=(const float*)d_in[4];
  const float* t_wv=(const float*)d_in[5];  const float* t_bv=(const float*)d_in[6];
  const float* t_wo=(const float*)d_in[7];  const float* t_bo=(const float*)d_in[8];
  const float* s_wq=(const float*)d_in[9];  const float* s_bq=(const float*)d_in[10];
  const float* s_wk=(const float*)d_in[11]; const float* s_bk=(const float*)d_in[12];
  const float* s_wv=(const float*)d_in[13]; const float* s_bv=(const float*)d_in[14];
  const float* s_wo=(const float*)d_in[15]; const float* s_bo=(const float*)d_in[16];
  const float* cluster=(const float*)d_in[17];
  const float* conv_w=(const float*)d_in[18]; const float* conv_b=(const float*)d_in[19];
  const float* r_wq=(const float*)d_in[20]; const float* r_bq=(const float*)d_in[21];
  const float* r_wk=(const float*)d_in[22]; const float* r_bk=(const float*)d_in[23];
  const float* r_wv=(const float*)d_in[24]; const float* r_bv=(const float*)d_in[25];
  const float* r_wo=(const float*)d_in[26]; const float* r_bo=(const float*)d_in[27];
  const float* ln_t1_g=(const float*)d_in[28]; const float* ln_t1_b=(const float*)d_in[29];
  const float* ln_t2_g=(const float*)d_in[30]; const float* ln_t2_b=(const float*)d_in[31];
  const float* ln_d1_g=(const float*)d_in[32]; const float* ln_d1_b=(const float*)d_in[33];
  const float* ln_d2_g=(const float*)d_in[34]; const float* ln_d2_b=(const float*)d_in[35];
  const float* ft_w1=(const float*)d_in[36]; const float* ft_b1=(const float*)d_in[37];
  const float* ft_w2=(const float*)d_in[38]; const float* ft_b2=(const float*)d_in[39];
  const float* fd_w1=(const float*)d_in[40]; const float* fd_b1=(const float*)d_in[41];
  const float* fd_w2=(const float*)d_in[42]; const float* fd_b2=(const float*)d_in[43];

  // Workspace: 3 big bf16 buffers + bf16 W^T pool + fp32 smalls (~108 MB)
  bf16* Ab = (bf16*)d_ws;
  bf16* Bb = Ab + NE;
  bf16* Cb = Bb + NE;
  bf16* WP = Cb + NE;                       // 1572864 bf16
  float* QSf   = (float*)(WP + 1572864);    // 240*256
  float* FEATf = QSf + 240*256;
  float* ROUTEf= FEATf + 1920*256;
  float* KRf   = ROUTEf + 1920*256;
  float* VRf   = KRf + 1920*256;
  int*   IDXb  = (int*)(VRf + 1920*256);    // 15360*33

  // ---- weight prep: fp32 [K][N] -> bf16 [N][K] ----
  WPrep wp;
  const float* wsrc[12] = {t_wq,t_wk,t_wv,t_wo,s_wk,s_wv,r_wq,r_wo,ft_w1,ft_w2,fd_w1,fd_w2};
  int wK[12] = {256,256,256,256,256,256,256,256,256,1024,256,1024};
  int wN[12] = {256,256,256,256,256,256,256,256,1024,256,1024,256};
  int off = 0, toff = 0;
  for (int i=0;i<12;++i) {
    wp.src[i]=wsrc[i]; wp.K[i]=wK[i]; wp.N[i]=wN[i];
    wp.dstoff[i]=off; wp.tileoff[i]=toff;
    off += wK[i]*wN[i];
    toff += (wK[i]/32)*(wN[i]/32);
  }
  wp.tileoff[12]=toff;
  prep_w_k<<<toff, 256, 0, stream>>>(wp, WP);
  bf16* Wq=WP+wp.dstoff[0]; bf16* Wk=WP+wp.dstoff[1]; bf16* Wv=WP+wp.dstoff[2];
  bf16* Wo=WP+wp.dstoff[3]; bf16* Wsk=WP+wp.dstoff[4]; bf16* Wsv=WP+wp.dstoff[5];
  bf16* Wrq=WP+wp.dstoff[6]; bf16* Wro=WP+wp.dstoff[7];
  bf16* Wf1=WP+wp.dstoff[8]; bf16* Wf2=WP+wp.dstoff[9];
  bf16* Wd1=WP+wp.dstoff[10]; bf16* Wd2=WP+wp.dstoff[11];

  dim3 blk(256);
  const int STRIPE = NROWS/4;               // 15408
  dim3 gBig(2, (NROWS+127)/128);            // N=256 GEMMs on full M
  dim3 gS1(8, (STRIPE+127)/128);            // N=1024 FFN up
  dim3 gS2(2, (STRIPE+127)/128);            // N=256  FFN down
  dim3 gQ(4, 4);                            // old kernel, M=240
  dim3 gSmall(4, 30);                       // old kernel, M=1920

  // ---- Route 1: temporal ----
  mgemm_k<<<gBig, blk, 0, stream>>>(queries, Wq, t_bq, nullptr, Ab, NROWS, 256, 256, MF_AF32);
  mgemm_k<<<gBig, blk, 0, stream>>>(queries, Wk, t_bk, nullptr, Bb, NROWS, 256, 256, MF_AF32);
  mgemm_k<<<gBig, blk, 0, stream>>>(queries, Wv, t_bv, nullptr, Cb, NROWS, 256, 256, MF_AF32);
  attn1_k<<<BV, 128, 0, stream>>>(Ab, Bb, Cb);                        // O -> Ab
  mgemm_k<<<gBig, blk, 0, stream>>>(Ab, Wo, t_bo, queries, Bb, NROWS, 256, 256, MF_RF32);
  ln_k<<<NROWS/4, blk, 0, stream>>>(Bb, Ab, ln_t1_g, ln_t1_b, NROWS); // x1 -> Ab
  for (int st = 0; st < 4; ++st) {
    size_t ro = (size_t)st * STRIPE * DD;
    mgemm_k<<<gS1, blk, 0, stream>>>(Ab + ro, Wf1, ft_b1, nullptr, Cb, STRIPE, 1024, 256, MF_GELU);
    mgemm_k<<<gS2, blk, 0, stream>>>(Cb, Wf2, ft_b2, Ab + ro, Bb + ro, STRIPE, 256, 1024, 0);
  }
  ln_k<<<NROWS/4, blk, 0, stream>>>(Bb, Ab, ln_t2_g, ln_t2_b, NROWS); // x -> Ab

  // ---- Route 2: dimensional ----
  transpose_k<<<NROWS, 64, 0, stream>>>(Ab, Bb);                      // xd -> Bb
  mgemm_k<<<gBig, blk, 0, stream>>>(Bb, Wsk, s_bk, nullptr, Ab, NROWS, 256, 256, MF_LOGRELU); // kS
  mgemm_k<<<gBig, blk, 0, stream>>>(Bb, Wsv, s_bv, nullptr, Cb, NROWS, 256, 256, MF_LOGRELU); // vS
  gemm_k<<<gQ, blk, 0, stream>>>(cluster, s_wq, s_bq, nullptr, QSf, 240, 256, 256, 0);
  topk_k<<<BSEG*HH*GG, 64, 0, stream>>>(QSf, Ab, IDXb);
  conv_k<<<BSEG*GG, blk, 0, stream>>>(Cb, IDXb, conv_w, conv_b, FEATf);
  gemm_k<<<gSmall, blk, 0, stream>>>(FEATf, s_wo, s_bo, nullptr, ROUTEf, 1920, 256, 256, 0);
  mgemm_k<<<gBig, blk, 0, stream>>>(Bb, Wrq, r_bq, nullptr, Ab, NROWS, 256, 256, 0);       // qD -> Ab
  gemm_k<<<gSmall, blk, 0, stream>>>(ROUTEf, r_wk, r_bk, nullptr, KRf, 1920, 256, 256, 0);
  gemm_k<<<gSmall, blk, 0, stream>>>(ROUTEf, r_wv, r_bv, nullptr, VRf, 1920, 256, 256, 0);
  attn2_k<<<BSEG, blk, 0, stream>>>(Ab, KRf, VRf);                    // O -> Ab
  mgemm_k<<<gBig, blk, 0, stream>>>(Ab, Wro, r_bo, Bb, Cb, NROWS, 256, 256, 0);            // + xd -> Cb
  ln_k<<<NROWS/4, blk, 0, stream>>>(Cb, Ab, ln_d1_g, ln_d1_b, NROWS); // x1d -> Ab
  for (int st = 0; st < 4; ++st) {
    size_t ro = (size_t)st * STRIPE * DD;
    mgemm_k<<<gS1, blk, 0, stream>>>(Ab + ro, Wd1, fd_b1, nullptr, Bb, STRIPE, 1024, 256, MF_GELU);
    mgemm_k<<<gS2, blk, 0, stream>>>(Bb, Wd2, fd_b2, Ab + ro, Cb + ro, STRIPE, 256, 1024, 0);
  }
  ln_out_k<<<NROWS/4, blk, 0, stream>>>(Cb, (float*)d_out, ln_d2_g, ln_d2_b);
}